// Round 6
// baseline (303.585 us; speedup 1.0000x reference)
//
#include <hip/hip_runtime.h>
#include <hip/hip_bf16.h>
#include <math.h>

#define L_TOK 4096
#define D_DIM 576
#define NHEADS 8
#define DHEAD 72
#define DPAD 96
#define HSZ ((size_t)NHEADS * L_TOK * DPAD)   // elems per Q/K/V tensor
#define KSPLIT 3

typedef __attribute__((ext_vector_type(8))) short short8;
typedef __attribute__((ext_vector_type(4))) short short4v;
typedef __attribute__((ext_vector_type(4))) float float4v;

// ---------------------------------------------------------------------------
// K1: unfold 3x3 stride 2 pad 1 -> xb bf16 [4096][576]
// ---------------------------------------------------------------------------
__global__ __launch_bounds__(256) void unfold_kernel(const float* __restrict__ fea,
                                                     __hip_bfloat16* __restrict__ x) {
  int idx = blockIdx.x * 256 + threadIdx.x;   // over 64*4096
  int c = idx >> 12;
  int l = idx & 4095;
  int ho = l >> 6, wo = l & 63;
  const float* f = fea + (size_t)c * (128 * 128);
  __hip_bfloat16* xr = x + (size_t)l * D_DIM + c * 9;
#pragma unroll
  for (int ki = 0; ki < 3; ki++) {
    int h = 2 * ho + ki - 1;
#pragma unroll
    for (int kj = 0; kj < 3; kj++) {
      int w = 2 * wo + kj - 1;
      float v = 0.f;
      if ((unsigned)h < 128u && (unsigned)w < 128u) v = f[h * 128 + w];
      xr[ki * 3 + kj] = __float2bfloat16(v);
    }
  }
}

// ---------------------------------------------------------------------------
// fused weight prep: w_qkv^T, w_out^T (fp32->bf16 transpose), conv_w cvt
// ---------------------------------------------------------------------------
__device__ inline void tc_body(const float* __restrict__ src,
                               __hip_bfloat16* __restrict__ dst, int R, int C,
                               int bi, int bj, int t, __hip_bfloat16* Ts) {
  const int col = t & 63, row4 = t >> 6;
#pragma unroll
  for (int u = 0; u < 16; u++) {
    int r = u * 4 + row4;
    Ts[r * 68 + col] = __float2bfloat16(src[(size_t)(bj * 64 + r) * C + bi * 64 + col]);
  }
  __syncthreads();
#pragma unroll
  for (int u = 0; u < 16; u++) {
    int c = u * 4 + row4;
    dst[(size_t)(bi * 64 + c) * R + bj * 64 + col] = Ts[col * 68 + c];
  }
}

__global__ __launch_bounds__(256) void prep_weights(const float* __restrict__ w_qkv,
                                                    const float* __restrict__ w_out,
                                                    const float* __restrict__ conv_w,
                                                    __hip_bfloat16* __restrict__ WqkvT,
                                                    __hip_bfloat16* __restrict__ WoT,
                                                    __hip_bfloat16* __restrict__ CwB) {
  __shared__ __hip_bfloat16 Ts[64 * 68];
  int b = blockIdx.x;
  int t = threadIdx.x;
  if (b < 243) {                    // w_qkv: [576][1728] -> [1728][576]
    tc_body(w_qkv, WqkvT, D_DIM, 1728, b % 27, b / 27, t, Ts);
  } else if (b < 324) {             // w_out: [576][576] -> [576][576]^T
    b -= 243;
    tc_body(w_out, WoT, D_DIM, D_DIM, b % 9, b / 9, t, Ts);
  } else {                          // conv_w: elementwise cvt, 128*576 elems
    int i = (b - 324) * 256 + t;
    CwB[i] = __float2bfloat16(conv_w[i]);
  }
}

// ---------------------------------------------------------------------------
// bf16 MFMA GEMM: C[M][N] = A[M][576] @ Bt[N][576]^T (+epilogue)
// BM=128, BN=64, BK=64; 4 waves in 2x2 (wave m-tile 64, n-tile 32).
// EPI: 0 = QKV scatter(+bias): Q,K -> [h][L][96]; V -> VbT [h][96][L]
//      1 = oproj(+bias+residual->bf16), 2 = SiLU+store^T (fp32 out)
// ---------------------------------------------------------------------------
template <int EPI>
__global__ __launch_bounds__(256) void gemm_mfma(const __hip_bfloat16* __restrict__ A,
                                                 const __hip_bfloat16* __restrict__ Bt,
                                                 const float* __restrict__ bias,
                                                 const __hip_bfloat16* __restrict__ resid,
                                                 __hip_bfloat16* __restrict__ outB,
                                                 __hip_bfloat16* __restrict__ outB2,
                                                 float* __restrict__ outF) {
  constexpr int K = D_DIM;
  __shared__ __align__(16) __hip_bfloat16 As[128 * 72];
  __shared__ __align__(16) __hip_bfloat16 Bs[64 * 72];
  const int t = threadIdx.x;
  const int wave = t >> 6, lane = t & 63, quad = lane >> 4, l16 = lane & 15;
  const int wm = (wave & 2) * 32;   // 0 or 64
  const int wn = (wave & 1) * 32;   // 0 or 32
  const int m0 = blockIdx.x * 128, n0 = blockIdx.y * 64;

  float4v acc[4][2];
#pragma unroll
  for (int i = 0; i < 4; i++)
#pragma unroll
    for (int j = 0; j < 2; j++) acc[i][j] = (float4v){0.f, 0.f, 0.f, 0.f};

  const int arow = t >> 3, ach = t & 7;
  for (int k0 = 0; k0 < K; k0 += 64) {
    __syncthreads();
#pragma unroll
    for (int u = 0; u < 4; u++) {
      int row = u * 32 + arow;
      *(float4*)(&As[row * 72 + ach * 8]) =
          *(const float4*)(A + (size_t)(m0 + row) * K + k0 + ach * 8);
    }
#pragma unroll
    for (int u = 0; u < 2; u++) {
      int row = u * 32 + arow;
      *(float4*)(&Bs[row * 72 + ach * 8]) =
          *(const float4*)(Bt + (size_t)(n0 + row) * K + k0 + ach * 8);
    }
    __syncthreads();
    short8 af[4][2], bfr[2][2];
#pragma unroll
    for (int i = 0; i < 4; i++)
#pragma unroll
      for (int s = 0; s < 2; s++)
        af[i][s] = *(const short8*)(&As[(wm + i * 16 + l16) * 72 + s * 32 + quad * 8]);
#pragma unroll
    for (int j = 0; j < 2; j++)
#pragma unroll
      for (int s = 0; s < 2; s++)
        bfr[j][s] = *(const short8*)(&Bs[(wn + j * 16 + l16) * 72 + s * 32 + quad * 8]);
#pragma unroll
    for (int i = 0; i < 4; i++)
#pragma unroll
      for (int j = 0; j < 2; j++) {
        acc[i][j] = __builtin_amdgcn_mfma_f32_16x16x32_bf16(af[i][0], bfr[j][0], acc[i][j], 0, 0, 0);
        acc[i][j] = __builtin_amdgcn_mfma_f32_16x16x32_bf16(af[i][1], bfr[j][1], acc[i][j], 0, 0, 0);
      }
  }

  // epilogue; C/D layout: col = l16 (n), row = quad*4 + r (m)
  if (EPI == 0) {
    const int part = n0 / D_DIM;          // block lies in exactly one of Q/K/V
#pragma unroll
    for (int j = 0; j < 2; j++) {
      int ng = n0 + wn + j * 16 + l16;
      float bv = bias[ng];
      int rem = ng - part * D_DIM;
      int h = rem / DHEAD;
      int d = rem - h * DHEAD;
#pragma unroll
      for (int i = 0; i < 4; i++) {
        int mb = m0 + wm + i * 16 + quad * 4;
#pragma unroll
        for (int r = 0; r < 4; r++) {
          float v = acc[i][j][r] + bv;
          if (part < 2) {
            __hip_bfloat16* dst = outB + (size_t)part * HSZ;
            dst[((size_t)h * L_TOK + mb + r) * DPAD + d] = __float2bfloat16(v);
          } else {
            outB2[((size_t)h * DPAD + d) * L_TOK + mb + r] = __float2bfloat16(v);
          }
        }
      }
    }
  } else if (EPI == 1) {
#pragma unroll
    for (int j = 0; j < 2; j++) {
      int ng = n0 + wn + j * 16 + l16;
      float bv = bias[ng];
#pragma unroll
      for (int i = 0; i < 4; i++) {
        int mb = m0 + wm + i * 16 + quad * 4;
#pragma unroll
        for (int r = 0; r < 4; r++) {
          size_t idx = (size_t)(mb + r) * D_DIM + ng;
          float v = acc[i][j][r] + bv + __bfloat162float(resid[idx]);
          outB[idx] = __float2bfloat16(v);
        }
      }
    }
  } else {
#pragma unroll
    for (int j = 0; j < 2; j++) {
      int ng = n0 + wn + j * 16 + l16;   // output channel, <128
#pragma unroll
      for (int i = 0; i < 4; i++) {
        int mb = m0 + wm + i * 16 + quad * 4;
#pragma unroll
        for (int r = 0; r < 4; r++) {
          float v = acc[i][j][r];
          float sg = 1.f / (1.f + __expf(-v));
          outF[(size_t)ng * L_TOK + mb + r] = v * sg;
        }
      }
    }
  }
}

// ---------------------------------------------------------------------------
// bf16 MFMA flash attention, S^T formulation, BARRIER-FREE.
// No K/V LDS staging: MFMA fragments load directly from global (L2-resident;
// head->XCD affinity via bid&7). Only LDS use is the per-wave P round-trip
// (C-layout -> A-layout), which needs no __syncthreads (same-wave ordering).
// K-pad d>=72 is uninitialized garbage but multiplies zeroed Q-frag slots;
// V-pad rows pollute only O cols 72..79, which merge ignores.
// WG = 4 waves x 32 queries = 128 q; grid 768 = 32 qblk x 3 ksplit x 8 heads.
// ---------------------------------------------------------------------------
#define PS_STRIDE 72

__global__ __launch_bounds__(256) void attn_mfma(const __hip_bfloat16* __restrict__ Qb,
                                                 const __hip_bfloat16* __restrict__ Kb,
                                                 const __hip_bfloat16* __restrict__ VbT,
                                                 __hip_bfloat16* __restrict__ Opart,
                                                 float* __restrict__ Ml) {
  __shared__ __align__(16) __hip_bfloat16 Ps[4 * 32 * PS_STRIDE];  // 18432 B

  const int bid = blockIdx.x;
  const int h = bid & 7;                  // head -> XCD affinity
  const int rest = bid >> 3;
  const int ksp = rest % KSPLIT;
  const int qblk = rest / KSPLIT;         // 0..31
  const int t = threadIdx.x;
  const int wave = t >> 6;
  const int lane = t & 63;
  const int quad = lane >> 4;
  const int l16 = lane & 15;

  const __hip_bfloat16* Qh = Qb + (size_t)h * L_TOK * DPAD;
  const __hip_bfloat16* Kh = Kb + (size_t)h * L_TOK * DPAD;
  const __hip_bfloat16* VhT = VbT + (size_t)h * DPAD * L_TOK;

  // Q as MFMA B operand: lane holds Q[q=l16][d=s*32+quad*8+j]; d>=72 pad -> 0
  const int qbase = qblk * 128 + wave * 32;
  short8 qf[2][3];
#pragma unroll
  for (int mi = 0; mi < 2; mi++) {
#pragma unroll
    for (int s = 0; s < 3; s++) {
      if (s == 2 && quad >= 1) {
        qf[mi][s] = (short8){0, 0, 0, 0, 0, 0, 0, 0};
      } else {
        qf[mi][s] = *(const short8*)(Qh + (size_t)(qbase + mi * 16 + l16) * DPAD + s * 32 + quad * 8);
      }
    }
  }

  float4v Of[2][5];
#pragma unroll
  for (int mi = 0; mi < 2; mi++)
#pragma unroll
    for (int nt = 0; nt < 5; nt++) Of[mi][nt] = (float4v){0.f, 0.f, 0.f, 0.f};
  float mrow[2] = {-INFINITY, -INFINITY};   // per-lane stats for query q=l16 (+16*mi)
  float lrow[2] = {0.f, 0.f};
  const float scale = 0.11785113019775792f;  // 72^-0.5

  __hip_bfloat16* myPs = Ps + wave * 32 * PS_STRIDE;
  const int kstart = ksp * 1408;                 // 22 tiles * 64 keys
  const int ntiles = (ksp == 2) ? 20 : 22;

  for (int kt = 0; kt < ntiles; kt++) {
    const int kbase = kstart + kt * 64;

    // S^T = K Q^T: A = K-frag direct from global (shared across both q-frags)
    float4v S[2][4];
#pragma unroll
    for (int ks = 0; ks < 4; ks++) {
      float4v a0 = (float4v){0.f, 0.f, 0.f, 0.f};
      float4v a1 = (float4v){0.f, 0.f, 0.f, 0.f};
      const __hip_bfloat16* krow = Kh + (size_t)(kbase + ks * 16 + l16) * DPAD + quad * 8;
#pragma unroll
      for (int s = 0; s < 3; s++) {
        short8 kf = *(const short8*)(krow + s * 32);
        a0 = __builtin_amdgcn_mfma_f32_16x16x32_bf16(kf, qf[0][s], a0, 0, 0, 0);
        a1 = __builtin_amdgcn_mfma_f32_16x16x32_bf16(kf, qf[1][s], a1, 0, 0, 0);
      }
#pragma unroll
      for (int r = 0; r < 4; r++) { S[0][ks][r] = a0[r] * scale; S[1][ks][r] = a1[r] * scale; }
    }

    // softmax: each lane holds 16 scores (keys ks*16+quad*4+r) for query l16
    float alpha[2];
#pragma unroll
    for (int mi = 0; mi < 2; mi++) {
      float tm = -INFINITY;
#pragma unroll
      for (int ks = 0; ks < 4; ks++)
#pragma unroll
        for (int r = 0; r < 4; r++) tm = fmaxf(tm, S[mi][ks][r]);
      tm = fmaxf(tm, __shfl_xor(tm, 16));
      tm = fmaxf(tm, __shfl_xor(tm, 32));
      float mnew = fmaxf(mrow[mi], tm);
      alpha[mi] = __expf(mrow[mi] - mnew);
      mrow[mi] = mnew;
      float ps = 0.f;
#pragma unroll
      for (int ks = 0; ks < 4; ks++)
#pragma unroll
        for (int r = 0; r < 4; r++) {
          float p = __expf(S[mi][ks][r] - mnew);
          ps += p;
          S[mi][ks][r] = p;
        }
      ps += __shfl_xor(ps, 16);
      ps += __shfl_xor(ps, 32);
      lrow[mi] = lrow[mi] * alpha[mi] + ps;
    }

    // P writes: Ps[q][key], 4 consecutive keys packed per ds_write_b64
#pragma unroll
    for (int mi = 0; mi < 2; mi++) {
#pragma unroll
      for (int ks = 0; ks < 4; ks++) {
        union { short4v v; __hip_bfloat16 hh[4]; } pk;
#pragma unroll
        for (int r = 0; r < 4; r++) pk.hh[r] = __float2bfloat16(S[mi][ks][r]);
        *(short4v*)(&myPs[(mi * 16 + l16) * PS_STRIDE + ks * 16 + quad * 4]) = pk.v;
      }
    }

    // redistribute alpha from query=l16 lanes to O-row lanes (row = quad*4+r)
    float aq[2][4];
#pragma unroll
    for (int mi = 0; mi < 2; mi++)
#pragma unroll
      for (int r = 0; r < 4; r++) aq[mi][r] = __shfl(alpha[mi], quad * 4 + r);
#pragma unroll
    for (int mi = 0; mi < 2; mi++)
#pragma unroll
      for (int nt = 0; nt < 5; nt++)
#pragma unroll
        for (int r = 0; r < 4; r++) Of[mi][nt][r] *= aq[mi][r];

    // O += P V : A = P (per-wave LDS, in-order), B = V^T frag direct from global
#pragma unroll
    for (int kstep = 0; kstep < 2; kstep++) {
      short8 pa0 = *(const short8*)(&myPs[(0 + l16) * PS_STRIDE + kstep * 32 + quad * 8]);
      short8 pa1 = *(const short8*)(&myPs[(16 + l16) * PS_STRIDE + kstep * 32 + quad * 8]);
      const __hip_bfloat16* vrow = VhT + (size_t)l16 * L_TOK + kbase + kstep * 32 + quad * 8;
#pragma unroll
      for (int nt = 0; nt < 5; nt++) {
        short8 vb = *(const short8*)(vrow + (size_t)(nt * 16) * L_TOK);
        Of[0][nt] = __builtin_amdgcn_mfma_f32_16x16x32_bf16(pa0, vb, Of[0][nt], 0, 0, 0);
        Of[1][nt] = __builtin_amdgcn_mfma_f32_16x16x32_bf16(pa1, vb, Of[1][nt], 0, 0, 0);
      }
    }
  }

  // store unnormalized partials + m,l
  const size_t pb = ((size_t)ksp * NHEADS + h) * L_TOK;
#pragma unroll
  for (int mi = 0; mi < 2; mi++) {
#pragma unroll
    for (int nt = 0; nt < 5; nt++) {
      int d = nt * 16 + l16;
#pragma unroll
      for (int r = 0; r < 4; r++) {
        int q = qbase + mi * 16 + quad * 4 + r;
        Opart[(pb + q) * 80 + d] = __float2bfloat16(Of[mi][nt][r]);
      }
    }
  }
  if (quad == 0) {   // lanes 0..15 hold stats for q = qbase + mi*16 + l16
#pragma unroll
    for (int mi = 0; mi < 2; mi++) {
      int q = qbase + mi * 16 + l16;
      Ml[(pb + q) * 2] = mrow[mi];
      Ml[(pb + q) * 2 + 1] = lrow[mi];
    }
  }
}

// ---------------------------------------------------------------------------
// flash-merge of the KSPLIT partials -> ob[q][h*72+d] bf16
// ---------------------------------------------------------------------------
__global__ __launch_bounds__(256) void attn_merge(const __hip_bfloat16* __restrict__ Opart,
                                                  const float* __restrict__ Ml,
                                                  __hip_bfloat16* __restrict__ ob) {
  int idx = blockIdx.x * 256 + threadIdx.x;     // 8h * 4096q * 9ch
  int h = idx / (L_TOK * 9);
  int rem = idx - h * (L_TOK * 9);
  int q = rem / 9;
  int ch = rem - q * 9;
  size_t b[KSPLIT];
  float m[KSPLIT], l[KSPLIT];
  float mx = -INFINITY;
#pragma unroll
  for (int s = 0; s < KSPLIT; s++) {
    b[s] = ((size_t)s * NHEADS + h) * L_TOK + q;
    m[s] = Ml[b[s] * 2];
    l[s] = Ml[b[s] * 2 + 1];
    mx = fmaxf(mx, m[s]);
  }
  float w[KSPLIT], denom = 0.f;
#pragma unroll
  for (int s = 0; s < KSPLIT; s++) {
    w[s] = __expf(m[s] - mx);
    denom += w[s] * l[s];
  }
  float inv = 1.f / denom;
  float acc[8] = {0, 0, 0, 0, 0, 0, 0, 0};
#pragma unroll
  for (int s = 0; s < KSPLIT; s++) {
    short8 o = *(const short8*)(Opart + b[s] * 80 + ch * 8);
#pragma unroll
    for (int j = 0; j < 8; j++) {
      union { short ss; __hip_bfloat16 bb; } u;
      u.ss = o[j];
      acc[j] += w[s] * __bfloat162float(u.bb);
    }
  }
  __hip_bfloat16* dst = ob + (size_t)q * D_DIM + h * DHEAD + ch * 8;
#pragma unroll
  for (int j = 0; j < 8; j++) dst[j] = __float2bfloat16(acc[j] * inv);
}

// ---------------------------------------------------------------------------
extern "C" void kernel_launch(void* const* d_in, const int* in_sizes, int n_in,
                              void* d_out, int out_size, void* d_ws, size_t ws_size,
                              hipStream_t stream) {
  const float* fea    = (const float*)d_in[0];
  const float* w_qkv  = (const float*)d_in[1];
  const float* b_qkv  = (const float*)d_in[2];
  const float* w_out  = (const float*)d_in[3];
  const float* b_out  = (const float*)d_in[4];
  const float* conv_w = (const float*)d_in[5];
  float* out = (float*)d_out;

  __hip_bfloat16* xb    = (__hip_bfloat16*)d_ws;             // 4096*576
  __hip_bfloat16* WqkvT = xb + (size_t)L_TOK * D_DIM;        // 1728*576
  __hip_bfloat16* WoT   = WqkvT + (size_t)1728 * D_DIM;      // 576*576
  __hip_bfloat16* CwB   = WoT + (size_t)D_DIM * D_DIM;       // 128*576
  __hip_bfloat16* QKb   = CwB + (size_t)128 * D_DIM;         // 2 * HSZ (Q,K)
  __hip_bfloat16* VbT   = QKb + 2 * HSZ;                     // HSZ
  __hip_bfloat16* ob    = VbT + HSZ;                         // 4096*576
  __hip_bfloat16* xr    = ob + (size_t)L_TOK * D_DIM;        // 4096*576
  __hip_bfloat16* Opart = xr + (size_t)L_TOK * D_DIM;        // KSPLIT*8*4096*80
  float* Ml = (float*)(Opart + (size_t)KSPLIT * NHEADS * L_TOK * 80);  // KSPLIT*8*4096*2

  unfold_kernel<<<1024, 256, 0, stream>>>(fea, xb);
  prep_weights<<<612, 256, 0, stream>>>(w_qkv, w_out, conv_w, WqkvT, WoT, CwB);

  gemm_mfma<0><<<dim3(32, 27), 256, 0, stream>>>(xb, WqkvT, b_qkv, nullptr, QKb, VbT, nullptr);
  attn_mfma<<<768, 256, 0, stream>>>(QKb, QKb + HSZ, VbT, Opart, Ml);
  attn_merge<<<1152, 256, 0, stream>>>(Opart, Ml, ob);
  gemm_mfma<1><<<dim3(32, 9), 256, 0, stream>>>(ob, WoT, b_out, xb, xr, nullptr, nullptr);
  gemm_mfma<2><<<dim3(32, 2), 256, 0, stream>>>(xr, CwB, nullptr, nullptr, nullptr, nullptr, out);
}

// Round 7
// 225.007 us; speedup vs baseline: 1.3492x; 1.3492x over previous
//
#include <hip/hip_runtime.h>
#include <hip/hip_bf16.h>
#include <math.h>

#define L_TOK 4096
#define D_DIM 576
#define NHEADS 8
#define DHEAD 72
#define DPAD 96
#define HSZ ((size_t)NHEADS * L_TOK * DPAD)   // elems per Q/K/V tensor
#define KSPLIT 4

typedef __attribute__((ext_vector_type(8))) short short8;
typedef __attribute__((ext_vector_type(4))) short short4v;
typedef __attribute__((ext_vector_type(4))) float float4v;

// ---------------------------------------------------------------------------
// K1: unfold 3x3 stride 2 pad 1 -> xb bf16 [4096][576]
// lane-major in c: consecutive threads write adjacent 18B chunks (coalesced).
// ---------------------------------------------------------------------------
__global__ __launch_bounds__(256) void unfold_kernel(const float* __restrict__ fea,
                                                     __hip_bfloat16* __restrict__ x) {
  int idx = blockIdx.x * 256 + threadIdx.x;   // over 64*4096
  int c = idx & 63;
  int l = idx >> 6;
  int ho = l >> 6, wo = l & 63;
  const float* f = fea + (size_t)c * (128 * 128);
  __hip_bfloat16* xr = x + (size_t)l * D_DIM + c * 9;
#pragma unroll
  for (int ki = 0; ki < 3; ki++) {
    int h = 2 * ho + ki - 1;
#pragma unroll
    for (int kj = 0; kj < 3; kj++) {
      int w = 2 * wo + kj - 1;
      float v = 0.f;
      if ((unsigned)h < 128u && (unsigned)w < 128u) v = f[h * 128 + w];
      xr[ki * 3 + kj] = __float2bfloat16(v);
    }
  }
}

// ---------------------------------------------------------------------------
// fused weight prep: w_qkv^T, w_out^T (fp32->bf16 transpose), conv_w cvt
// ---------------------------------------------------------------------------
__device__ inline void tc_body(const float* __restrict__ src,
                               __hip_bfloat16* __restrict__ dst, int R, int C,
                               int bi, int bj, int t, __hip_bfloat16* Ts) {
  const int col = t & 63, row4 = t >> 6;
#pragma unroll
  for (int u = 0; u < 16; u++) {
    int r = u * 4 + row4;
    Ts[r * 68 + col] = __float2bfloat16(src[(size_t)(bj * 64 + r) * C + bi * 64 + col]);
  }
  __syncthreads();
#pragma unroll
  for (int u = 0; u < 16; u++) {
    int c = u * 4 + row4;
    dst[(size_t)(bi * 64 + c) * R + bj * 64 + col] = Ts[col * 68 + c];
  }
}

__global__ __launch_bounds__(256) void prep_weights(const float* __restrict__ w_qkv,
                                                    const float* __restrict__ w_out,
                                                    const float* __restrict__ conv_w,
                                                    __hip_bfloat16* __restrict__ WqkvT,
                                                    __hip_bfloat16* __restrict__ WoT,
                                                    __hip_bfloat16* __restrict__ CwB) {
  __shared__ __hip_bfloat16 Ts[64 * 68];
  int b = blockIdx.x;
  int t = threadIdx.x;
  if (b < 243) {                    // w_qkv: [576][1728] -> [1728][576]
    tc_body(w_qkv, WqkvT, D_DIM, 1728, b % 27, b / 27, t, Ts);
  } else if (b < 324) {             // w_out: [576][576] -> [576][576]^T
    b -= 243;
    tc_body(w_out, WoT, D_DIM, D_DIM, b % 9, b / 9, t, Ts);
  } else {                          // conv_w: elementwise cvt, 128*576 elems
    int i = (b - 324) * 256 + t;
    CwB[i] = __float2bfloat16(conv_w[i]);
  }
}

// ---------------------------------------------------------------------------
// bf16 MFMA GEMM: C[M][N] = A[M][576] @ Bt[N][576]^T (+epilogue)
// BM=128, BN=64, BK=64; 4 waves in 2x2 (wave m-tile 64, n-tile 32).
// EPI: 0 = QKV scatter(+bias): Q,K -> [h][L][96]; V -> VbT [h][96][L]
//      1 = oproj(+bias+residual->bf16)
// ---------------------------------------------------------------------------
template <int EPI>
__global__ __launch_bounds__(256) void gemm_mfma(const __hip_bfloat16* __restrict__ A,
                                                 const __hip_bfloat16* __restrict__ Bt,
                                                 const float* __restrict__ bias,
                                                 const __hip_bfloat16* __restrict__ resid,
                                                 __hip_bfloat16* __restrict__ outB,
                                                 __hip_bfloat16* __restrict__ outB2) {
  constexpr int K = D_DIM;
  __shared__ __align__(16) __hip_bfloat16 As[128 * 72];
  __shared__ __align__(16) __hip_bfloat16 Bs[64 * 72];
  const int t = threadIdx.x;
  const int wave = t >> 6, lane = t & 63, quad = lane >> 4, l16 = lane & 15;
  const int wm = (wave & 2) * 32;   // 0 or 64
  const int wn = (wave & 1) * 32;   // 0 or 32
  const int m0 = blockIdx.x * 128, n0 = blockIdx.y * 64;

  float4v acc[4][2];
#pragma unroll
  for (int i = 0; i < 4; i++)
#pragma unroll
    for (int j = 0; j < 2; j++) acc[i][j] = (float4v){0.f, 0.f, 0.f, 0.f};

  const int arow = t >> 3, ach = t & 7;
  for (int k0 = 0; k0 < K; k0 += 64) {
    __syncthreads();
#pragma unroll
    for (int u = 0; u < 4; u++) {
      int row = u * 32 + arow;
      *(float4*)(&As[row * 72 + ach * 8]) =
          *(const float4*)(A + (size_t)(m0 + row) * K + k0 + ach * 8);
    }
#pragma unroll
    for (int u = 0; u < 2; u++) {
      int row = u * 32 + arow;
      *(float4*)(&Bs[row * 72 + ach * 8]) =
          *(const float4*)(Bt + (size_t)(n0 + row) * K + k0 + ach * 8);
    }
    __syncthreads();
    short8 af[4][2], bfr[2][2];
#pragma unroll
    for (int i = 0; i < 4; i++)
#pragma unroll
      for (int s = 0; s < 2; s++)
        af[i][s] = *(const short8*)(&As[(wm + i * 16 + l16) * 72 + s * 32 + quad * 8]);
#pragma unroll
    for (int j = 0; j < 2; j++)
#pragma unroll
      for (int s = 0; s < 2; s++)
        bfr[j][s] = *(const short8*)(&Bs[(wn + j * 16 + l16) * 72 + s * 32 + quad * 8]);
#pragma unroll
    for (int i = 0; i < 4; i++)
#pragma unroll
      for (int j = 0; j < 2; j++) {
        acc[i][j] = __builtin_amdgcn_mfma_f32_16x16x32_bf16(af[i][0], bfr[j][0], acc[i][j], 0, 0, 0);
        acc[i][j] = __builtin_amdgcn_mfma_f32_16x16x32_bf16(af[i][1], bfr[j][1], acc[i][j], 0, 0, 0);
      }
  }

  // epilogue; C/D layout: col = l16 (n), row = quad*4 + r (m)
  if (EPI == 0) {
    const int part = n0 / D_DIM;          // block lies in exactly one of Q/K/V
#pragma unroll
    for (int j = 0; j < 2; j++) {
      int ng = n0 + wn + j * 16 + l16;
      float bv = bias[ng];
      int rem = ng - part * D_DIM;
      int h = rem / DHEAD;
      int d = rem - h * DHEAD;
#pragma unroll
      for (int i = 0; i < 4; i++) {
        int mb = m0 + wm + i * 16 + quad * 4;
#pragma unroll
        for (int r = 0; r < 4; r++) {
          float v = acc[i][j][r] + bv;
          if (part < 2) {
            __hip_bfloat16* dst = outB + (size_t)part * HSZ;
            dst[((size_t)h * L_TOK + mb + r) * DPAD + d] = __float2bfloat16(v);
          } else {
            outB2[((size_t)h * DPAD + d) * L_TOK + mb + r] = __float2bfloat16(v);
          }
        }
      }
    }
  } else {
#pragma unroll
    for (int j = 0; j < 2; j++) {
      int ng = n0 + wn + j * 16 + l16;
      float bv = bias[ng];
#pragma unroll
      for (int i = 0; i < 4; i++) {
        int mb = m0 + wm + i * 16 + quad * 4;
#pragma unroll
        for (int r = 0; r < 4; r++) {
          size_t idx = (size_t)(mb + r) * D_DIM + ng;
          float v = acc[i][j][r] + bv + __bfloat162float(resid[idx]);
          outB[idx] = __float2bfloat16(v);
        }
      }
    }
  }
}

// ---------------------------------------------------------------------------
// final conv GEMM + SiLU, small tiles for full-GPU occupancy.
// BM=64, BN=32, grid (64,4)=256 WGs. out[oc][l] = silu(xr[l]·conv_w[oc])
// ---------------------------------------------------------------------------
__global__ __launch_bounds__(256) void final_small(const __hip_bfloat16* __restrict__ A,
                                                   const __hip_bfloat16* __restrict__ Bt,
                                                   float* __restrict__ out) {
  __shared__ __align__(16) __hip_bfloat16 As[64 * 72];
  __shared__ __align__(16) __hip_bfloat16 Bs[32 * 72];
  const int t = threadIdx.x;
  const int wave = t >> 6, lane = t & 63, quad = lane >> 4, l16 = lane & 15;
  const int wm = (wave & 2) * 16;   // 0 or 32
  const int wn = (wave & 1) * 16;   // 0 or 16
  const int m0 = blockIdx.x * 64, n0 = blockIdx.y * 32;

  float4v acc[2];
  acc[0] = (float4v){0.f, 0.f, 0.f, 0.f};
  acc[1] = (float4v){0.f, 0.f, 0.f, 0.f};

  const int arow = t >> 3, ach = t & 7;
  for (int k0 = 0; k0 < D_DIM; k0 += 64) {
    __syncthreads();
#pragma unroll
    for (int u = 0; u < 2; u++) {
      int row = u * 32 + arow;
      *(float4*)(&As[row * 72 + ach * 8]) =
          *(const float4*)(A + (size_t)(m0 + row) * D_DIM + k0 + ach * 8);
    }
    if (arow < 32)
      *(float4*)(&Bs[arow * 72 + ach * 8]) =
          *(const float4*)(Bt + (size_t)(n0 + arow) * D_DIM + k0 + ach * 8);
    __syncthreads();
    short8 af[2][2], bfr[2];
#pragma unroll
    for (int i = 0; i < 2; i++)
#pragma unroll
      for (int s = 0; s < 2; s++)
        af[i][s] = *(const short8*)(&As[(wm + i * 16 + l16) * 72 + s * 32 + quad * 8]);
#pragma unroll
    for (int s = 0; s < 2; s++)
      bfr[s] = *(const short8*)(&Bs[(wn + l16) * 72 + s * 32 + quad * 8]);
#pragma unroll
    for (int i = 0; i < 2; i++) {
      acc[i] = __builtin_amdgcn_mfma_f32_16x16x32_bf16(af[i][0], bfr[0], acc[i], 0, 0, 0);
      acc[i] = __builtin_amdgcn_mfma_f32_16x16x32_bf16(af[i][1], bfr[1], acc[i], 0, 0, 0);
    }
  }
  const int oc = n0 + wn + l16;
#pragma unroll
  for (int i = 0; i < 2; i++) {
    int mb = m0 + wm + i * 16 + quad * 4;
#pragma unroll
    for (int r = 0; r < 4; r++) {
      float v = acc[i][r];
      float sg = 1.f / (1.f + __expf(-v));
      out[(size_t)oc * L_TOK + mb + r] = v * sg;
    }
  }
}

// ---------------------------------------------------------------------------
// bf16 MFMA flash attention, S^T formulation, LDS-staged K/V, 64 q per wave.
// WG = 4 waves x 64 q = 256 q; grid 512 = 16 qblk x 4 ksplit x 8 heads.
// Per tile: 2 barriers; 88 MFMA per wave (4 q-frags reuse each K/V frag).
// Pads: Q-frag d>=72 zeroed in regs (kills K-pad garbage); Ks pad cols
// zeroed ONCE (stale-LDS NaN guard); V-pad rows only feed O cols 72..79,
// never read by merge (ws 0xAA poison is finite bf16).
// ---------------------------------------------------------------------------
#define KS_STRIDE 104
#define VT_STRIDE 72
#define PS_STRIDE 72

__global__ __launch_bounds__(256, 2) void attn_mfma(const __hip_bfloat16* __restrict__ Qb,
                                                    const __hip_bfloat16* __restrict__ Kb,
                                                    const __hip_bfloat16* __restrict__ VbT,
                                                    __hip_bfloat16* __restrict__ Opart,
                                                    float* __restrict__ Ml) {
  __shared__ __align__(16) __hip_bfloat16 Ks[64 * KS_STRIDE];      // 13312 B
  __shared__ __align__(16) __hip_bfloat16 Vt[80 * VT_STRIDE];      // 11520 B
  __shared__ __align__(16) __hip_bfloat16 Ps[4 * 64 * PS_STRIDE];  // 36864 B

  const int bid = blockIdx.x;
  const int h = bid & 7;                  // head -> XCD affinity
  const int rest = bid >> 3;
  const int ksp = rest & 3;
  const int qblk = rest >> 2;             // 0..15
  const int t = threadIdx.x;
  const int wave = t >> 6;
  const int lane = t & 63;
  const int quad = lane >> 4;
  const int l16 = lane & 15;

  const __hip_bfloat16* Qh = Qb + (size_t)h * L_TOK * DPAD;
  const __hip_bfloat16* Kh = Kb + (size_t)h * L_TOK * DPAD;
  const __hip_bfloat16* VhT = VbT + (size_t)h * DPAD * L_TOK;

  // Q as MFMA B operand: lane holds Q[q=l16][d=s*32+quad*8+j]; d>=72 pad -> 0
  const int qbase = qblk * 256 + wave * 64;
  short8 qf[4][3];
#pragma unroll
  for (int mi = 0; mi < 4; mi++) {
#pragma unroll
    for (int s = 0; s < 3; s++) {
      if (s == 2 && quad >= 1) {
        qf[mi][s] = (short8){0, 0, 0, 0, 0, 0, 0, 0};
      } else {
        qf[mi][s] = *(const short8*)(Qh + (size_t)(qbase + mi * 16 + l16) * DPAD + s * 32 + quad * 8);
      }
    }
  }

  // one-time zero of Ks pad cols 72..95 (guards against stale-LDS NaN)
  const float4 zero4 = {0.f, 0.f, 0.f, 0.f};
  if (t < 192) {
    int row = t / 3, ch = 9 + t % 3;
    *(float4*)(&Ks[row * KS_STRIDE + ch * 8]) = zero4;
  }

  float4v Of[4][5];
#pragma unroll
  for (int mi = 0; mi < 4; mi++)
#pragma unroll
    for (int nt = 0; nt < 5; nt++) Of[mi][nt] = (float4v){0.f, 0.f, 0.f, 0.f};
  float mrow[4] = {-INFINITY, -INFINITY, -INFINITY, -INFINITY};
  float lrow[4] = {0.f, 0.f, 0.f, 0.f};
  const float scale = 0.11785113019775792f;  // 72^-0.5

  __hip_bfloat16* myPs = Ps + wave * 64 * PS_STRIDE;
  const int kstart = ksp * 1024;            // 16 tiles * 64 keys

  for (int kt = 0; kt < 16; kt++) {
    const int kbase = kstart + kt * 64;
    __syncthreads();  // prior tile's K/V reads complete

    // stage K tile [64 keys][d<72] : 576 chunks
    for (int e = t; e < 576; e += 256) {
      int row = e / 9, ch = e - row * 9;
      *(float4*)(&Ks[row * KS_STRIDE + ch * 8]) =
          *(const float4*)(Kh + (size_t)(kbase + row) * DPAD + ch * 8);
    }
    // stage V^T tile [80 d][64 keys] : 640 chunks (d>=72 garbage but finite)
    for (int e = t; e < 640; e += 256) {
      int d = e >> 3, ch = e & 7;
      *(float4*)(&Vt[d * VT_STRIDE + ch * 8]) =
          *(const float4*)(VhT + (size_t)d * L_TOK + kbase + ch * 8);
    }
    __syncthreads();

    // S^T = K Q^T: A = K-frag (shared across 4 q-frags), B = Q-frag
    float4v S[4][4];
#pragma unroll
    for (int ks = 0; ks < 4; ks++) {
      float4v a0 = (float4v){0.f, 0.f, 0.f, 0.f};
      float4v a1 = a0, a2 = a0, a3 = a0;
#pragma unroll
      for (int s = 0; s < 3; s++) {
        short8 kf = *(const short8*)(&Ks[(ks * 16 + l16) * KS_STRIDE + s * 32 + quad * 8]);
        a0 = __builtin_amdgcn_mfma_f32_16x16x32_bf16(kf, qf[0][s], a0, 0, 0, 0);
        a1 = __builtin_amdgcn_mfma_f32_16x16x32_bf16(kf, qf[1][s], a1, 0, 0, 0);
        a2 = __builtin_amdgcn_mfma_f32_16x16x32_bf16(kf, qf[2][s], a2, 0, 0, 0);
        a3 = __builtin_amdgcn_mfma_f32_16x16x32_bf16(kf, qf[3][s], a3, 0, 0, 0);
      }
#pragma unroll
      for (int r = 0; r < 4; r++) {
        S[0][ks][r] = a0[r] * scale;
        S[1][ks][r] = a1[r] * scale;
        S[2][ks][r] = a2[r] * scale;
        S[3][ks][r] = a3[r] * scale;
      }
    }

    // softmax: lane holds 16 scores (keys ks*16+quad*4+r) for query l16(+16mi)
    float alpha[4];
#pragma unroll
    for (int mi = 0; mi < 4; mi++) {
      float tm = -INFINITY;
#pragma unroll
      for (int ks = 0; ks < 4; ks++)
#pragma unroll
        for (int r = 0; r < 4; r++) tm = fmaxf(tm, S[mi][ks][r]);
      tm = fmaxf(tm, __shfl_xor(tm, 16));
      tm = fmaxf(tm, __shfl_xor(tm, 32));
      float mnew = fmaxf(mrow[mi], tm);
      alpha[mi] = __expf(mrow[mi] - mnew);
      mrow[mi] = mnew;
      float ps = 0.f;
#pragma unroll
      for (int ks = 0; ks < 4; ks++)
#pragma unroll
        for (int r = 0; r < 4; r++) {
          float p = __expf(S[mi][ks][r] - mnew);
          ps += p;
          S[mi][ks][r] = p;
        }
      ps += __shfl_xor(ps, 16);
      ps += __shfl_xor(ps, 32);
      lrow[mi] = lrow[mi] * alpha[mi] + ps;
    }

    // P writes: Ps[q][key], 4 consecutive keys packed per ds_write_b64
#pragma unroll
    for (int mi = 0; mi < 4; mi++) {
#pragma unroll
      for (int ks = 0; ks < 4; ks++) {
        union { short4v v; __hip_bfloat16 hh[4]; } pk;
#pragma unroll
        for (int r = 0; r < 4; r++) pk.hh[r] = __float2bfloat16(S[mi][ks][r]);
        *(short4v*)(&myPs[(mi * 16 + l16) * PS_STRIDE + ks * 16 + quad * 4]) = pk.v;
      }
    }

    // redistribute alpha from query=l16 lanes to O-row lanes (row = quad*4+r)
    float aq[4][4];
#pragma unroll
    for (int mi = 0; mi < 4; mi++)
#pragma unroll
      for (int r = 0; r < 4; r++) aq[mi][r] = __shfl(alpha[mi], quad * 4 + r);
#pragma unroll
    for (int mi = 0; mi < 4; mi++)
#pragma unroll
      for (int nt = 0; nt < 5; nt++)
#pragma unroll
        for (int r = 0; r < 4; r++) Of[mi][nt][r] *= aq[mi][r];

    // O += P V : A = P (per-wave LDS, same-wave in-order), B = V-frag
#pragma unroll
    for (int kstep = 0; kstep < 2; kstep++) {
      short8 pa[4];
#pragma unroll
      for (int mi = 0; mi < 4; mi++)
        pa[mi] = *(const short8*)(&myPs[(mi * 16 + l16) * PS_STRIDE + kstep * 32 + quad * 8]);
#pragma unroll
      for (int nt = 0; nt < 5; nt++) {
        short8 vb = *(const short8*)(&Vt[(nt * 16 + l16) * VT_STRIDE + kstep * 32 + quad * 8]);
        Of[0][nt] = __builtin_amdgcn_mfma_f32_16x16x32_bf16(pa[0], vb, Of[0][nt], 0, 0, 0);
        Of[1][nt] = __builtin_amdgcn_mfma_f32_16x16x32_bf16(pa[1], vb, Of[1][nt], 0, 0, 0);
        Of[2][nt] = __builtin_amdgcn_mfma_f32_16x16x32_bf16(pa[2], vb, Of[2][nt], 0, 0, 0);
        Of[3][nt] = __builtin_amdgcn_mfma_f32_16x16x32_bf16(pa[3], vb, Of[3][nt], 0, 0, 0);
      }
    }
  }

  // store unnormalized partials + m,l
  const size_t pb = ((size_t)ksp * NHEADS + h) * L_TOK;
#pragma unroll
  for (int mi = 0; mi < 4; mi++) {
#pragma unroll
    for (int nt = 0; nt < 5; nt++) {
      int d = nt * 16 + l16;
#pragma unroll
      for (int r = 0; r < 4; r++) {
        int q = qbase + mi * 16 + quad * 4 + r;
        Opart[(pb + q) * 80 + d] = __float2bfloat16(Of[mi][nt][r]);
      }
    }
  }
  if (quad == 0) {   // lanes 0..15 hold stats for q = qbase + mi*16 + l16
#pragma unroll
    for (int mi = 0; mi < 4; mi++) {
      int q = qbase + mi * 16 + l16;
      Ml[(pb + q) * 2] = mrow[mi];
      Ml[(pb + q) * 2 + 1] = lrow[mi];
    }
  }
}

// ---------------------------------------------------------------------------
// flash-merge of the KSPLIT partials -> ob[q][h*72+d] bf16
// ---------------------------------------------------------------------------
__global__ __launch_bounds__(256) void attn_merge(const __hip_bfloat16* __restrict__ Opart,
                                                  const float* __restrict__ Ml,
                                                  __hip_bfloat16* __restrict__ ob) {
  int idx = blockIdx.x * 256 + threadIdx.x;     // 8h * 4096q * 9ch
  int h = idx / (L_TOK * 9);
  int rem = idx - h * (L_TOK * 9);
  int q = rem / 9;
  int ch = rem - q * 9;
  size_t b[KSPLIT];
  float m[KSPLIT], l[KSPLIT];
  float mx = -INFINITY;
#pragma unroll
  for (int s = 0; s < KSPLIT; s++) {
    b[s] = ((size_t)s * NHEADS + h) * L_TOK + q;
    m[s] = Ml[b[s] * 2];
    l[s] = Ml[b[s] * 2 + 1];
    mx = fmaxf(mx, m[s]);
  }
  float w[KSPLIT], denom = 0.f;
#pragma unroll
  for (int s = 0; s < KSPLIT; s++) {
    w[s] = __expf(m[s] - mx);
    denom += w[s] * l[s];
  }
  float inv = 1.f / denom;
  float acc[8] = {0, 0, 0, 0, 0, 0, 0, 0};
#pragma unroll
  for (int s = 0; s < KSPLIT; s++) {
    short8 o = *(const short8*)(Opart + b[s] * 80 + ch * 8);
#pragma unroll
    for (int j = 0; j < 8; j++) {
      union { short ss; __hip_bfloat16 bb; } u;
      u.ss = o[j];
      acc[j] += w[s] * __bfloat162float(u.bb);
    }
  }
  __hip_bfloat16* dst = ob + (size_t)q * D_DIM + h * DHEAD + ch * 8;
#pragma unroll
  for (int j = 0; j < 8; j++) dst[j] = __float2bfloat16(acc[j] * inv);
}

// ---------------------------------------------------------------------------
extern "C" void kernel_launch(void* const* d_in, const int* in_sizes, int n_in,
                              void* d_out, int out_size, void* d_ws, size_t ws_size,
                              hipStream_t stream) {
  const float* fea    = (const float*)d_in[0];
  const float* w_qkv  = (const float*)d_in[1];
  const float* b_qkv  = (const float*)d_in[2];
  const float* w_out  = (const float*)d_in[3];
  const float* b_out  = (const float*)d_in[4];
  const float* conv_w = (const float*)d_in[5];
  float* out = (float*)d_out;

  __hip_bfloat16* xb    = (__hip_bfloat16*)d_ws;             // 4096*576
  __hip_bfloat16* WqkvT = xb + (size_t)L_TOK * D_DIM;        // 1728*576
  __hip_bfloat16* WoT   = WqkvT + (size_t)1728 * D_DIM;      // 576*576
  __hip_bfloat16* CwB   = WoT + (size_t)D_DIM * D_DIM;       // 128*576
  __hip_bfloat16* QKb   = CwB + (size_t)128 * D_DIM;         // 2 * HSZ (Q,K)
  __hip_bfloat16* VbT   = QKb + 2 * HSZ;                     // HSZ
  __hip_bfloat16* ob    = VbT + HSZ;                         // 4096*576
  __hip_bfloat16* Opart = ob + (size_t)L_TOK * D_DIM;        // KSPLIT*8*4096*80
  float* Ml = (float*)(Opart + (size_t)KSPLIT * NHEADS * L_TOK * 80);  // KSPLIT*8*4096*2
  // xr aliases Opart: Opart is dead after attn_merge, before gemm_mfma<1> runs
  __hip_bfloat16* xr    = Opart;

  unfold_kernel<<<1024, 256, 0, stream>>>(fea, xb);
  prep_weights<<<612, 256, 0, stream>>>(w_qkv, w_out, conv_w, WqkvT, WoT, CwB);

  gemm_mfma<0><<<dim3(32, 27), 256, 0, stream>>>(xb, WqkvT, b_qkv, nullptr, QKb, VbT);
  attn_mfma<<<512, 256, 0, stream>>>(QKb, QKb + HSZ, VbT, Opart, Ml);
  attn_merge<<<1152, 256, 0, stream>>>(Opart, Ml, ob);
  gemm_mfma<1><<<dim3(32, 9), 256, 0, stream>>>(ob, WoT, b_out, xb, xr, nullptr);
  final_small<<<dim3(64, 4), 256, 0, stream>>>(xr, CwB, out);
}